// Round 10
// baseline (501.331 us; speedup 1.0000x reference)
//
#include <hip/hip_runtime.h>
#include <hip/hip_bf16.h>

typedef __attribute__((ext_vector_type(8))) short short8_t;
typedef __attribute__((ext_vector_type(4))) float f32x4;
typedef __attribute__((ext_vector_type(4))) unsigned int u32x4;

#define KINST 100000
#define KPAD  100096   // 3128 * 32
#define NB2   3128     // blocks of 32 rows
#define DIMIN 768
#define DIMEMB 512
#define DIMATTN 384

__device__ __forceinline__ unsigned short f2bf(float f) {
    unsigned int u = __builtin_bit_cast(unsigned int, f);
    u = u + 0x7FFFu + ((u >> 16) & 1u);       // RNE
    return (unsigned short)(u >> 16);
}
__device__ __forceinline__ unsigned int packbf(float a, float b) {
    return (unsigned int)f2bf(a) | ((unsigned int)f2bf(b) << 16);
}
__device__ __forceinline__ float bf2f(unsigned short h) {
    unsigned int u = ((unsigned int)h) << 16;
    return __builtin_bit_cast(float, u);
}
__device__ __forceinline__ float fast_tanh(float x) {
    const float e2 = __expf(2.f * x);
    return (e2 - 1.f) * __builtin_amdgcn_rcpf(e2 + 1.f);
}

// ---------------- prep: plain K-tiled bf16 transposed weights (round-6 verified) ----------------
// WpTt: [t<24][n<512][c<4][e<8], value = bf16(Wproj[(t*32 + c*8 + e)*512 + n])
// W1Tt: [t<8][n<384][c<8][e<8],  value = bf16(W1[(t*64 + c*8 + e)*384 + n])
__global__ __launch_bounds__(256) void k_prep(
    const float* __restrict__ Wproj, const float* __restrict__ W1,
    unsigned short* __restrict__ WpTt, unsigned short* __restrict__ W1Tt)
{
    const int idx = blockIdx.x * 256 + threadIdx.x;
    if (idx < 49152) {                 // 24*512*4
        const int t = idx >> 11, r = idx & 2047;
        const int n = r >> 2, c = r & 3;
        short8_t v;
        #pragma unroll
        for (int e = 0; e < 8; ++e)
            v[e] = (short)f2bf(Wproj[(size_t)(t * 32 + c * 8 + e) * DIMEMB + n]);
        *(short8_t*)&WpTt[t * 16384 + n * 32 + c * 8] = v;
    } else {
        const int j = idx - 49152;     // < 24576 = 8*384*8
        const int t = j / 3072, r = j % 3072;
        const int n = r >> 3, c = r & 7;
        short8_t v;
        #pragma unroll
        for (int e = 0; e < 8; ++e)
            v[e] = (short)f2bf(W1[(size_t)(t * 64 + c * 8 + e) * DIMATTN + n]);
        *(short8_t*)&W1Tt[t * 24576 + n * 64 + c * 8] = v;
    }
}

// ---------------- GEMM1: H = relu(X @ Wp + b); A-stationary, barrier-free K-loop ----------------
// Block = 32 rows. Stage whole 32x768 X-slab (bf16) into padded LDS once, sync once,
// then 24 K-steps with NO barriers: B frags from L2-hot WpTt, A frags ds_read, 16 MFMA.
// H stored SWIZZLED (round-4/9 format): row*512 + (col>>6)*64 + ((((col>>3)&7)^(row&7))<<3) + (col&7)
__global__ __launch_bounds__(256, 2) void k_gemm1(
    const float* __restrict__ X,
    const unsigned short* __restrict__ WpTt,
    const float* __restrict__ bproj,
    unsigned short* __restrict__ H)
{
    __shared__ unsigned short Xs[32][776];   // 48.5 KB, +8 pad
    const int tid = threadIdx.x;
    const int lane = tid & 63, w = tid >> 6;   // 4 waves; wave w -> cols w*128..+127
    const int g = lane >> 4, fr = lane & 15;
    const int brow = blockIdx.x * 32;

    // ---- stage A: thread (row = tid>>3, kseg = tid&7), 3 segments of 32 fp32 ----
    {
        const int row = tid >> 3, ks = (tid & 7) * 32;
        int grow = brow + row; if (grow >= KINST) grow = KINST - 1;
        const float* xs = X + (size_t)grow * DIMIN + ks;
        #pragma unroll
        for (int seg = 0; seg < 3; ++seg) {
            float4 f0 = *(const float4*)(xs + seg * 256);
            float4 f1 = *(const float4*)(xs + seg * 256 + 4);
            float4 f2 = *(const float4*)(xs + seg * 256 + 8);
            float4 f3 = *(const float4*)(xs + seg * 256 + 12);
            float4 f4 = *(const float4*)(xs + seg * 256 + 16);
            float4 f5 = *(const float4*)(xs + seg * 256 + 20);
            float4 f6 = *(const float4*)(xs + seg * 256 + 24);
            float4 f7 = *(const float4*)(xs + seg * 256 + 28);
            u32x4 p0, p1;
            p0[0] = packbf(f0.x, f0.y); p0[1] = packbf(f0.z, f0.w);
            p0[2] = packbf(f1.x, f1.y); p0[3] = packbf(f1.z, f1.w);
            p1[0] = packbf(f2.x, f2.y); p1[1] = packbf(f2.z, f2.w);
            p1[2] = packbf(f3.x, f3.y); p1[3] = packbf(f3.z, f3.w);
            *(u32x4*)&Xs[row][seg * 256 + ks % 32 == 0 ? seg * 256 + ks : seg * 256 + ks] = p0; // placeholder avoided below
            // (explicit addressing below)
            *(u32x4*)&Xs[row][seg * 256 + ks]      = p0;
            *(u32x4*)&Xs[row][seg * 256 + ks + 8]  = p1;
            u32x4 p2, p3;
            p2[0] = packbf(f4.x, f4.y); p2[1] = packbf(f4.z, f4.w);
            p2[2] = packbf(f5.x, f5.y); p2[3] = packbf(f5.z, f5.w);
            p3[0] = packbf(f6.x, f6.y); p3[1] = packbf(f6.z, f6.w);
            p3[2] = packbf(f7.x, f7.y); p3[3] = packbf(f7.z, f7.w);
            *(u32x4*)&Xs[row][seg * 256 + ks + 16] = p2;
            *(u32x4*)&Xs[row][seg * 256 + ks + 24] = p3;
        }
    }
    __syncthreads();

    // ---- barrier-free K-loop ----
    const unsigned short* gB = WpTt + (size_t)(w * 128 + fr) * 32 + g * 8;
    f32x4 acc[2][8] = {};
    #pragma unroll 4
    for (int t = 0; t < 24; ++t) {
        short8_t Bf[8];
        const unsigned short* gBt = gB + (size_t)t * 16384;
        #pragma unroll
        for (int j = 0; j < 8; ++j)
            Bf[j] = *(const short8_t*)(gBt + j * 512);
        short8_t af[2];
        #pragma unroll
        for (int i = 0; i < 2; ++i)
            af[i] = *(const short8_t*)&Xs[i * 16 + fr][t * 32 + g * 8];
        #pragma unroll
        for (int j = 0; j < 8; ++j)
            #pragma unroll
            for (int i = 0; i < 2; ++i)
                acc[i][j] = __builtin_amdgcn_mfma_f32_16x16x32_bf16(af[i], Bf[j], acc[i][j], 0, 0, 0);
    }

    // ---- epilogue: bias + relu, SWIZZLED bf16 H store ----
    #pragma unroll
    for (int j = 0; j < 8; ++j) {
        const int col = w * 128 + j * 16 + fr;
        const float bias = bproj[col];
        const int tile = (col >> 6) << 6, cc = (col >> 3) & 7, lo = col & 7;
        #pragma unroll
        for (int i = 0; i < 2; ++i) {
            #pragma unroll
            for (int r = 0; r < 4; ++r) {
                const int row = i * 16 + g * 4 + r;
                const int grow = brow + row;
                const float v = fmaxf(acc[i][j][r] + bias, 0.f);
                H[(size_t)grow * DIMEMB + tile + ((cc ^ (row & 7)) << 3) + lo] =
                    (grow < KINST) ? f2bf(v) : (unsigned short)0;
            }
        }
    }
}

// -------- GEMM2 fused: scores + E + pooling; A-stationary, barrier-free K-loop --------
// Block = 32 H-rows de-swizzled into padded LDS; 16 K-steps (BK=32) vs L2-hot W1;
// then tanh/W2 reduce -> E -> pool from LDS.
__global__ __launch_bounds__(256, 2) void k_gemm2(
    const unsigned short* __restrict__ H,
    const unsigned short* __restrict__ W1Tt,
    const float* __restrict__ b1,
    const float* __restrict__ W2,
    const float* __restrict__ b2,
    float* __restrict__ Spart,
    float* __restrict__ Mpart)
{
    __shared__ unsigned short Hs[32][520];   // 32.5 KB, +8 pad, PLAIN layout
    __shared__ float sred[4][32];
    __shared__ float Elds[32];
    __shared__ float red[4][512];            // 8 KB
    const int tid = threadIdx.x;
    const int lane = tid & 63, w = tid >> 6;  // 4 waves; wave w -> cols w*96..+95
    const int g = lane >> 4, fr = lane & 15;
    const int brow = blockIdx.x * 32;

    // ---- stage: de-swizzle H rows into plain padded LDS ----
    {
        const int row = tid >> 3, c8 = tid & 7;     // row 0..31, 64-col tile c8
        const int grow = brow + row;                 // < KPAD, pad rows are zeros
        const unsigned short* hsrc = H + (size_t)grow * DIMEMB + c8 * 64;
        #pragma unroll
        for (int q = 0; q < 8; ++q) {
            const short8_t v = *(const short8_t*)(hsrc + ((q ^ (row & 7)) << 3));
            *(short8_t*)&Hs[row][c8 * 64 + q * 8] = v;
        }
    }
    __syncthreads();

    // ---- barrier-free K-loop: a2 = H @ W1 ----
    const unsigned short* gB = W1Tt + (size_t)(w * 96 + fr) * 64 + g * 8;
    f32x4 a2[2][6] = {};
    #pragma unroll 4
    for (int t = 0; t < 16; ++t) {
        short8_t Bf[6];
        const unsigned short* gBt = gB + (size_t)(t >> 1) * 24576 + (t & 1) * 32;
        #pragma unroll
        for (int j = 0; j < 6; ++j)
            Bf[j] = *(const short8_t*)(gBt + j * 1024);
        short8_t af[2];
        #pragma unroll
        for (int i = 0; i < 2; ++i)
            af[i] = *(const short8_t*)&Hs[i * 16 + fr][t * 32 + g * 8];
        #pragma unroll
        for (int j = 0; j < 6; ++j)
            #pragma unroll
            for (int i = 0; i < 2; ++i)
                a2[i][j] = __builtin_amdgcn_mfma_f32_16x16x32_bf16(af[i], Bf[j], a2[i][j], 0, 0, 0);
    }

    // ---- scores: tanh + W2, reduce over cols ----
    float ps[2][4] = {};
    #pragma unroll
    for (int j = 0; j < 6; ++j) {
        const int col = w * 96 + j * 16 + fr;
        const float bb = b1[col], ww = W2[col];
        #pragma unroll
        for (int i = 0; i < 2; ++i)
            #pragma unroll
            for (int r = 0; r < 4; ++r)
                ps[i][r] += fast_tanh(a2[i][j][r] + bb) * ww;
    }
    #pragma unroll
    for (int off = 1; off < 16; off <<= 1)
        #pragma unroll
        for (int i = 0; i < 2; ++i)
            #pragma unroll
            for (int r = 0; r < 4; ++r)
                ps[i][r] += __shfl_xor(ps[i][r], off, 64);
    if (fr == 0) {
        #pragma unroll
        for (int i = 0; i < 2; ++i)
            #pragma unroll
            for (int r = 0; r < 4; ++r)
                sred[w][i * 16 + g * 4 + r] = ps[i][r];
    }
    __syncthreads();
    {
        float myE = 0.f;
        if (tid < 32) {
            const int grow = brow + tid;
            const float s = sred[0][tid] + sred[1][tid] + sred[2][tid] + sred[3][tid] + b2[0];
            const float e = (grow < KINST) ? __expf(s) : 0.f;
            Elds[tid] = e;
            myE = e;
        }
        if (w == 0) {
            #pragma unroll
            for (int off = 1; off < 64; off <<= 1) myE += __shfl_xor(myE, off, 64);
            if (lane == 0) Spart[blockIdx.x] = myE;
        }
    }
    __syncthreads();

    // ---- pool: Mpart = sum E_r * H[r][:] from LDS ----
    float pa[8] = {};
    #pragma unroll
    for (int ii = 0; ii < 8; ++ii) {
        const int row = w * 8 + ii;
        const float e = Elds[row];
        const short8_t v = *(const short8_t*)&Hs[row][lane * 8];
        #pragma unroll
        for (int jj = 0; jj < 8; ++jj)
            pa[jj] += e * bf2f((unsigned short)v[jj]);
    }
    #pragma unroll
    for (int jj = 0; jj < 8; ++jj) red[w][lane * 8 + jj] = pa[jj];
    __syncthreads();
    #pragma unroll
    for (int u = 0; u < 2; ++u) {
        const int d = u * 256 + tid;
        Mpart[(size_t)blockIdx.x * DIMEMB + d] =
            red[0][d] + red[1][d] + red[2][d] + red[3][d];
    }
}

// ---------------- reduce Mpart[3128][512] -> Mred[16][512] ----------------
__global__ __launch_bounds__(512) void k_red(
    const float* __restrict__ Mpart, float* __restrict__ Mred)
{
    const int d = threadIdx.x;
    const int b = blockIdx.x;
    float m = 0.f;
    for (int r = b; r < NB2; r += 16)
        m += Mpart[(size_t)r * DIMEMB + d];
    Mred[b * DIMEMB + d] = m;
}

// ---------------- head: Spart/Mred reduce, router, top-5, logits ----------------
__global__ __launch_bounds__(1024) void k_head(
    const float* __restrict__ Spart,   // [3128]
    const float* __restrict__ Mred,    // [16][512]
    const float* __restrict__ Wr,      // [512][13]
    const float* __restrict__ Xtfl,    // [13][512]
    const float* __restrict__ Wp,      // [512][2]
    const float* __restrict__ bp,      // [2]
    float* __restrict__ outp)
{
    __shared__ float Mlds[512];
    __shared__ float logits[13];
    __shared__ float wsel[5];
    __shared__ int isel[5];
    __shared__ float Slds;
    __shared__ float swred[16];
    __shared__ float r0s[16], r1s[16];
    const int tid = threadIdx.x, lane = tid & 63, w = tid >> 6;

    float s = 0.f;
    for (int i = tid; i < NB2; i += 1024) s += Spart[i];
    #pragma unroll
    for (int off = 1; off < 64; off <<= 1) s += __shfl_xor(s, off, 64);
    if (lane == 0) swred[w] = s;

    float m = 0.f;
    if (tid < 512) {
        #pragma unroll
        for (int b = 0; b < 16; ++b) m += Mred[b * 512 + tid];
    }

    __syncthreads();
    if (tid == 0) {
        float t = 0.f;
        #pragma unroll
        for (int i = 0; i < 16; ++i) t += swred[i];
        Slds = t;
    }
    __syncthreads();
    if (tid < 512) Mlds[tid] = m / Slds;
    __syncthreads();
    if (tid < 13) {
        float l = 0.f;
        for (int dd = 0; dd < 512; ++dd) l += Mlds[dd] * Wr[dd * 13 + tid];
        logits[tid] = l;
    }
    __syncthreads();
    if (tid == 0) {
        float mx = -1e30f;
        for (int i = 0; i < 13; ++i) mx = fmaxf(mx, logits[i]);
        float pe[13]; float sum = 0.f;
        for (int i = 0; i < 13; ++i) { pe[i] = __expf(logits[i] - mx); sum += pe[i]; }
        unsigned used = 0;
        for (int t = 0; t < 5; ++t) {
            int bi = 0; float bv = -1.f;
            for (int i = 0; i < 13; ++i)
                if (!((used >> i) & 1u) && pe[i] > bv) { bv = pe[i]; bi = i; }
            used |= (1u << bi);
            wsel[t] = bv / sum;
            isel[t] = bi;
        }
    }
    __syncthreads();
    float p0 = 0.f, p1 = 0.f;
    if (tid < 512) {
        float mo = 0.f;
        #pragma unroll
        for (int t = 0; t < 5; ++t) mo += wsel[t] * Xtfl[isel[t] * 512 + tid];
        p0 = mo * Wp[tid * 2 + 0];
        p1 = mo * Wp[tid * 2 + 1];
    }
    #pragma unroll
    for (int off = 1; off < 64; off <<= 1) {
        p0 += __shfl_xor(p0, off, 64);
        p1 += __shfl_xor(p1, off, 64);
    }
    if (lane == 0) { r0s[w] = p0; r1s[w] = p1; }
    __syncthreads();
    if (tid == 0) {
        float a = bp[0], b = bp[1];
        for (int i = 0; i < 16; ++i) { a += r0s[i]; b += r1s[i]; }
        outp[0] = a; outp[1] = b;
    }
}

extern "C" void kernel_launch(void* const* d_in, const int* in_sizes, int n_in,
                              void* d_out, int out_size, void* d_ws, size_t ws_size,
                              hipStream_t stream)
{
    const float* Xtfl  = (const float*)d_in[0];
    const float* X     = (const float*)d_in[1];
    const float* Wproj = (const float*)d_in[2];
    const float* bproj = (const float*)d_in[3];
    const float* W1    = (const float*)d_in[4];
    const float* b1    = (const float*)d_in[5];
    const float* W2    = (const float*)d_in[6];
    const float* b2    = (const float*)d_in[7];
    const float* Wr    = (const float*)d_in[8];
    const float* Wp    = (const float*)d_in[9];
    const float* bp    = (const float*)d_in[10];
    float* out = (float*)d_out;

    // ws layout (~110 MiB total)
    char* ws = (char*)d_ws;
    size_t off = 0;
    unsigned short* H    = (unsigned short*)(ws + off); off += (size_t)KPAD * DIMEMB * 2;
    unsigned short* WpTt = (unsigned short*)(ws + off); off += (size_t)DIMEMB * DIMIN * 2;
    unsigned short* W1Tt = (unsigned short*)(ws + off); off += (size_t)DIMATTN * DIMEMB * 2;
    float* Spart = (float*)(ws + off); off += (size_t)NB2 * 4 + 512;
    float* Mpart = (float*)(ws + off); off += (size_t)NB2 * DIMEMB * 4;
    float* Mred  = (float*)(ws + off); off += (size_t)16 * DIMEMB * 4;

    k_prep<<<288, 256, 0, stream>>>(Wproj, W1, WpTt, W1Tt);
    k_gemm1<<<NB2, 256, 0, stream>>>(X, WpTt, bproj, H);
    k_gemm2<<<NB2, 256, 0, stream>>>(H, W1Tt, b1, W2, b2, Spart, Mpart);
    k_red<<<16, 512, 0, stream>>>(Mpart, Mred);
    k_head<<<1, 1024, 0, stream>>>(Spart, Mred, Wr, Xtfl, Wp, bp, out);
}

// Round 11
// 415.837 us; speedup vs baseline: 1.2056x; 1.2056x over previous
//
#include <hip/hip_runtime.h>
#include <hip/hip_bf16.h>

typedef __attribute__((ext_vector_type(8))) short short8_t;
typedef __attribute__((ext_vector_type(4))) float f32x4;
typedef __attribute__((ext_vector_type(4))) unsigned int u32x4;

#define KINST 100000
#define KPAD  100096   // 782 * 128 = 3128 * 32
#define NB1   3128     // gemm1 blocks of 32 rows
#define DIMIN 768
#define DIMEMB 512
#define DIMATTN 384

__device__ __forceinline__ unsigned short f2bf(float f) {
    unsigned int u = __builtin_bit_cast(unsigned int, f);
    u = u + 0x7FFFu + ((u >> 16) & 1u);       // RNE
    return (unsigned short)(u >> 16);
}
__device__ __forceinline__ unsigned int packbf(float a, float b) {
    return (unsigned int)f2bf(a) | ((unsigned int)f2bf(b) << 16);
}
__device__ __forceinline__ float bf2f(unsigned short h) {
    unsigned int u = ((unsigned int)h) << 16;
    return __builtin_bit_cast(float, u);
}
__device__ __forceinline__ float fast_tanh(float x) {
    const float e2 = __expf(2.f * x);
    return (e2 - 1.f) * __builtin_amdgcn_rcpf(e2 + 1.f);
}
// async global->LDS, 16B per lane. LDS dest must be wave-uniform base + lane*16.
__device__ __forceinline__ void gll16(const unsigned short* g, unsigned short* l) {
    __builtin_amdgcn_global_load_lds(
        (const __attribute__((address_space(1))) unsigned int*)g,
        (__attribute__((address_space(3))) unsigned int*)l, 16, 0, 0);
}

// ---------------- prep (round-9 verified) ----------------
// WpTt (PLAIN): [t<24][n<512][c<4][e<8] = bf16(Wproj[(t*32+c*8+e)*512 + n])
// W1Ts (SWIZZLED): [t<8][n<384][cs<8][e<8], cs = c ^ (n&7) = bf16(W1[(t*64+c*8+e)*384 + n])
__global__ __launch_bounds__(256) void k_prep(
    const float* __restrict__ Wproj, const float* __restrict__ W1,
    unsigned short* __restrict__ WpTt, unsigned short* __restrict__ W1Ts)
{
    const int idx = blockIdx.x * 256 + threadIdx.x;
    if (idx < 49152) {                 // 24*512*4
        const int t = idx >> 11, r = idx & 2047;
        const int n = r >> 2, c = r & 3;
        short8_t v;
        #pragma unroll
        for (int e = 0; e < 8; ++e)
            v[e] = (short)f2bf(Wproj[(size_t)(t * 32 + c * 8 + e) * DIMEMB + n]);
        *(short8_t*)&WpTt[t * 16384 + n * 32 + c * 8] = v;
    } else {
        const int j = idx - 49152;     // < 24576 = 8*8*384
        const int t = j / 3072, r = j % 3072;
        const int c = r / 384, n = r % 384;
        short8_t v;
        #pragma unroll
        for (int e = 0; e < 8; ++e)
            v[e] = (short)f2bf(W1[(size_t)(t * 64 + c * 8 + e) * DIMATTN + n]);
        *(short8_t*)&W1Ts[t * 24576 + n * 64 + ((c ^ (n & 7)) << 3)] = v;
    }
}

// ---------------- GEMM1: H = relu(X @ Wp + b); A-stationary, barrier-free K-loop ----------------
// Block = 32 rows, BN=512 (wave w -> cols w*128..+127). Stage 32x768 X-slab once into
// Xs[t][row][32] (R6-verified 2-bit-XOR layout, 0 conflicts), sync once, then 24 K-steps
// with NO barriers: B reg-double-buffered from L2-hot WpTt, A frags via ds_read_b128.
// H stored SWIZZLED (round-4/9 format): row*512 + (col>>6)*64 + ((((col>>3)&7)^(row&7))<<3) + (col&7)
__global__ __launch_bounds__(256, 3) void k_gemm1(
    const float* __restrict__ X,
    const unsigned short* __restrict__ WpTt,
    const float* __restrict__ bproj,
    unsigned short* __restrict__ H)
{
    __shared__ unsigned short Xs[24 * 32 * 32];   // [t][row][32el], 48 KB
    const int tid = threadIdx.x;
    const int lane = tid & 63, w = tid >> 6;      // 4 waves; wave w -> cols w*128..+127
    const int g = lane >> 4, fr = lane & 15;
    const int brow = blockIdx.x * 32;

    // ---- stage: thread (row = tid>>3, tlo = tid&7) covers t = seg*8+tlo, one 32-el chunk ----
    {
        const int row = tid >> 3, tlo = tid & 7;
        int grow = brow + row; if (grow >= KINST) grow = KINST - 1;
        const float* xs = X + (size_t)grow * DIMIN + tlo * 32;
        const int key = (row >> 1) & 3;
        #pragma unroll
        for (int seg = 0; seg < 3; ++seg) {
            const int t = seg * 8 + tlo;
            float4 f[8];
            #pragma unroll
            for (int q = 0; q < 8; ++q)
                f[q] = *(const float4*)(xs + seg * 256 + q * 4);
            #pragma unroll
            for (int q = 0; q < 4; ++q) {
                u32x4 p;
                p[0] = packbf(f[2*q].x,   f[2*q].y);   p[1] = packbf(f[2*q].z,   f[2*q].w);
                p[2] = packbf(f[2*q+1].x, f[2*q+1].y); p[3] = packbf(f[2*q+1].z, f[2*q+1].w);
                *(u32x4*)&Xs[t * 1024 + row * 32 + ((q ^ key) << 3)] = p;
            }
        }
    }
    __syncthreads();

    // ---- barrier-free K-loop with B register double-buffer ----
    const unsigned short* gB = WpTt + (size_t)(w * 128 + fr) * 32 + g * 8;
    const int aro = (g ^ ((fr >> 1) & 3)) << 3;   // R6-verified frag read slot
    f32x4 acc[2][8] = {};
    short8_t Bf0[8], Bf1[8];
    #pragma unroll
    for (int j = 0; j < 8; ++j)
        Bf0[j] = *(const short8_t*)(gB + j * 512);

    for (int t = 0; t < 24; t += 2) {
        {   // prefetch B(t+1) -> Bf1 (rides over MFMA(t))
            const unsigned short* gBt = gB + (size_t)(t + 1) * 16384;
            #pragma unroll
            for (int j = 0; j < 8; ++j)
                Bf1[j] = *(const short8_t*)(gBt + j * 512);
        }
        {   // compute step t with Bf0
            short8_t af[2];
            #pragma unroll
            for (int i = 0; i < 2; ++i)
                af[i] = *(const short8_t*)&Xs[t * 1024 + (i * 16 + fr) * 32 + aro];
            #pragma unroll
            for (int j = 0; j < 8; ++j)
                #pragma unroll
                for (int i = 0; i < 2; ++i)
                    acc[i][j] = __builtin_amdgcn_mfma_f32_16x16x32_bf16(af[i], Bf0[j], acc[i][j], 0, 0, 0);
        }
        if (t + 2 < 24) {   // prefetch B(t+2) -> Bf0 (rides over MFMA(t+1))
            const unsigned short* gBt = gB + (size_t)(t + 2) * 16384;
            #pragma unroll
            for (int j = 0; j < 8; ++j)
                Bf0[j] = *(const short8_t*)(gBt + j * 512);
        }
        {   // compute step t+1 with Bf1
            short8_t af[2];
            #pragma unroll
            for (int i = 0; i < 2; ++i)
                af[i] = *(const short8_t*)&Xs[(t + 1) * 1024 + (i * 16 + fr) * 32 + aro];
            #pragma unroll
            for (int j = 0; j < 8; ++j)
                #pragma unroll
                for (int i = 0; i < 2; ++i)
                    acc[i][j] = __builtin_amdgcn_mfma_f32_16x16x32_bf16(af[i], Bf1[j], acc[i][j], 0, 0, 0);
        }
    }

    // ---- epilogue: bias + relu, SWIZZLED bf16 H store ----
    #pragma unroll
    for (int j = 0; j < 8; ++j) {
        const int col = w * 128 + j * 16 + fr;
        const float bias = bproj[col];
        const int tile = (col >> 6) << 6, cc = (col >> 3) & 7, lo = col & 7;
        #pragma unroll
        for (int i = 0; i < 2; ++i) {
            #pragma unroll
            for (int r = 0; r < 4; ++r) {
                const int row = i * 16 + g * 4 + r;
                const int grow = brow + row;
                const float v = fmaxf(acc[i][j][r] + bias, 0.f);
                H[(size_t)grow * DIMEMB + tile + ((cc ^ (row & 7)) << 3) + lo] =
                    (grow < KINST) ? f2bf(v) : (unsigned short)0;
            }
        }
    }
}

// -------- GEMM2 partial scores (round-4/9 verified, swizzled H) --------
__global__ __launch_bounds__(256) void k_gemm2(
    const unsigned short* __restrict__ H,
    const unsigned short* __restrict__ W1Ts,
    const float* __restrict__ b1,
    const float* __restrict__ W2,
    float* __restrict__ Tpart)
{
    __shared__ unsigned short As[2][8192];
    __shared__ unsigned short Bs[2][8192];
    __shared__ float sred[2][128];
    const int tid = threadIdx.x;
    const int lane = tid & 63, w = tid >> 6;
    const int wr = w >> 1, wc = w & 1;
    const int g = lane >> 4, fr = lane & 15;
    const int cb = blockIdx.x;               // 0..2
    const int brow = blockIdx.y * 128;
    const int bcol = cb * 128;

    const unsigned short* gA = H + (size_t)(brow + w * 32 + (lane >> 3)) * DIMEMB + (lane & 7) * 8;
    const unsigned short* gB = W1Ts + (size_t)(bcol + w * 32 + (lane >> 3)) * 64 + (lane & 7) * 8;
    const int loff = w * 2048 + lane * 8;

    f32x4 acc[4][4] = {};

    #pragma unroll
    for (int q = 0; q < 4; ++q) {
        gll16(gA + q * 4096, &As[0][loff + q * 512]);
        gll16(gB + q * 512,  &Bs[0][loff + q * 512]);
    }
    __syncthreads();

    for (int t = 0; t < 8; ++t) {
        const int buf = t & 1;
        if (t < 7) {
            #pragma unroll
            for (int q = 0; q < 4; ++q) {
                gll16(gA + (t + 1) * 64 + q * 4096,           &As[buf ^ 1][loff + q * 512]);
                gll16(gB + (size_t)(t + 1) * 24576 + q * 512, &Bs[buf ^ 1][loff + q * 512]);
            }
        }
        __builtin_amdgcn_s_setprio(1);
        #pragma unroll
        for (int kk = 0; kk < 2; ++kk) {
            short8_t af[4];
            #pragma unroll
            for (int i = 0; i < 4; ++i) {
                const int row = wr * 64 + i * 16 + fr;
                af[i] = *(const short8_t*)&As[buf][row * 64 + (((kk * 4 + g) ^ (fr & 7)) << 3)];
            }
            #pragma unroll
            for (int j = 0; j < 4; ++j) {
                const int rowb = wc * 64 + j * 16 + fr;
                const short8_t bf = *(const short8_t*)&Bs[buf][rowb * 64 + (((kk * 4 + g) ^ (fr & 7)) << 3)];
                #pragma unroll
                for (int i = 0; i < 4; ++i)
                    acc[i][j] = __builtin_amdgcn_mfma_f32_16x16x32_bf16(af[i], bf, acc[i][j], 0, 0, 0);
            }
        }
        __builtin_amdgcn_s_setprio(0);
        if (t < 7) __syncthreads();
    }

    float ps[4][4] = {};
    #pragma unroll
    for (int j = 0; j < 4; ++j) {
        const int col = bcol + wc * 64 + j * 16 + fr;
        const float bb = b1[col], ww = W2[col];
        #pragma unroll
        for (int i = 0; i < 4; ++i)
            #pragma unroll
            for (int r = 0; r < 4; ++r)
                ps[i][r] += fast_tanh(acc[i][j][r] + bb) * ww;
    }
    #pragma unroll
    for (int off = 1; off < 16; off <<= 1)
        #pragma unroll
        for (int i = 0; i < 4; ++i)
            #pragma unroll
            for (int r = 0; r < 4; ++r)
                ps[i][r] += __shfl_xor(ps[i][r], off, 64);
    if (fr == 0) {
        #pragma unroll
        for (int i = 0; i < 4; ++i)
            #pragma unroll
            for (int r = 0; r < 4; ++r)
                sred[wc][wr * 64 + i * 16 + g * 4 + r] = ps[i][r];
    }
    __syncthreads();
    if (tid < 128)
        Tpart[(size_t)cb * KPAD + brow + tid] = sred[0][tid] + sred[1][tid];
}

// ---------------- poolE (round-4/9 verified, swizzled H) ----------------
__global__ __launch_bounds__(512) void k_poolE(
    const float* __restrict__ Tpart,
    const unsigned short* __restrict__ H,
    const float* __restrict__ b2,
    float* __restrict__ Spart,
    float* __restrict__ Mpart)
{
    __shared__ float Elds[1024];
    __shared__ float red[8][512];
    __shared__ float ssum[8];
    const int tid = threadIdx.x, lane = tid & 63, w = tid >> 6;
    const int base = blockIdx.x * 1024;
    const float bb = b2[0];
    float es = 0.f;
    #pragma unroll
    for (int u = 0; u < 2; ++u) {
        const int r = base + u * 512 + tid;
        float e = 0.f;
        if (r < KINST)
            e = __expf(Tpart[r] + Tpart[KPAD + r] + Tpart[2 * KPAD + r] + bb);
        Elds[u * 512 + tid] = e;
        es += e;
    }
    #pragma unroll
    for (int off = 1; off < 64; off <<= 1) es += __shfl_xor(es, off, 64);
    if (lane == 0) ssum[w] = es;
    __syncthreads();
    if (tid == 0) {
        float t = 0.f;
        #pragma unroll
        for (int i = 0; i < 8; ++i) t += ssum[i];
        Spart[blockIdx.x] = t;
    }

    float pa[8] = {};
    const int tile = (lane >> 3) << 6, cf = lane & 7;
    for (int i = 0; i < 128; ++i) {
        const int lr = i * 8 + w;
        const float e = Elds[lr];
        if (e != 0.f) {                       // wave-uniform; guards OOB rows
            const int r = base + lr;
            const short8_t v = *(const short8_t*)(H + (size_t)r * DIMEMB + tile + ((cf ^ (r & 7)) << 3));
            #pragma unroll
            for (int j = 0; j < 8; ++j) pa[j] += e * bf2f((unsigned short)v[j]);
        }
    }
    #pragma unroll
    for (int j = 0; j < 8; ++j) red[w][lane * 8 + j] = pa[j];
    __syncthreads();
    float s2 = 0.f;
    #pragma unroll
    for (int k = 0; k < 8; ++k) s2 += red[k][tid];
    Mpart[(size_t)blockIdx.x * DIMEMB + tid] = s2;
}

// ---------------- head (round-4/9 verified) ----------------
__global__ __launch_bounds__(512) void k_head(
    const float* __restrict__ Spart,   // [98]
    const float* __restrict__ Mpart,   // [98][512]
    const float* __restrict__ Wr,      // [512][13]
    const float* __restrict__ Xtfl,    // [13][512]
    const float* __restrict__ Wp,      // [512][2]
    const float* __restrict__ bp,      // [2]
    float* __restrict__ outp)
{
    __shared__ float Mlds[512];
    __shared__ float logits[13];
    __shared__ float wsel[5];
    __shared__ int isel[5];
    __shared__ float Slds;
    __shared__ float swred[8];
    __shared__ float r0s[8], r1s[8];
    const int tid = threadIdx.x, lane = tid & 63, w = tid >> 6;

    float s = 0.f;
    if (tid < 98) s = Spart[tid];
    #pragma unroll
    for (int off = 1; off < 64; off <<= 1) s += __shfl_xor(s, off, 64);
    if (lane == 0) swred[w] = s;

    float m = 0.f;
    #pragma unroll 2
    for (int b = 0; b < 98; ++b) m += Mpart[(size_t)b * 512 + tid];

    __syncthreads();
    if (tid == 0) {
        float t = 0.f;
        #pragma unroll
        for (int i = 0; i < 8; ++i) t += swred[i];
        Slds = t;
    }
    __syncthreads();
    Mlds[tid] = m / Slds;
    __syncthreads();
    if (tid < 13) {
        float l = 0.f;
        for (int dd = 0; dd < 512; ++dd) l += Mlds[dd] * Wr[dd * 13 + tid];
        logits[tid] = l;
    }
    __syncthreads();
    if (tid == 0) {
        float mx = -1e30f;
        for (int i = 0; i < 13; ++i) mx = fmaxf(mx, logits[i]);
        float pe[13]; float sum = 0.f;
        for (int i = 0; i < 13; ++i) { pe[i] = __expf(logits[i] - mx); sum += pe[i]; }
        unsigned used = 0;
        for (int t = 0; t < 5; ++t) {
            int bi = 0; float bv = -1.f;
            for (int i = 0; i < 13; ++i)
                if (!((used >> i) & 1u) && pe[i] > bv) { bv = pe[i]; bi = i; }
            used |= (1u << bi);
            wsel[t] = bv / sum;
            isel[t] = bi;
        }
    }
    __syncthreads();
    float mo = 0.f;
    #pragma unroll
    for (int t = 0; t < 5; ++t) mo += wsel[t] * Xtfl[isel[t] * 512 + tid];
    float p0 = mo * Wp[tid * 2 + 0];
    float p1 = mo * Wp[tid * 2 + 1];
    #pragma unroll
    for (int off = 1; off < 64; off <<= 1) {
        p0 += __shfl_xor(p0, off, 64);
        p1 += __shfl_xor(p1, off, 64);
    }
    if (lane == 0) { r0s[w] = p0; r1s[w] = p1; }
    __syncthreads();
    if (tid == 0) {
        float a = bp[0], b = bp[1];
        for (int i = 0; i < 8; ++i) { a += r0s[i]; b += r1s[i]; }
        outp[0] = a; outp[1] = b;
    }
}

extern "C" void kernel_launch(void* const* d_in, const int* in_sizes, int n_in,
                              void* d_out, int out_size, void* d_ws, size_t ws_size,
                              hipStream_t stream)
{
    const float* Xtfl  = (const float*)d_in[0];
    const float* X     = (const float*)d_in[1];
    const float* Wproj = (const float*)d_in[2];
    const float* bproj = (const float*)d_in[3];
    const float* W1    = (const float*)d_in[4];
    const float* b1    = (const float*)d_in[5];
    const float* W2    = (const float*)d_in[6];
    const float* b2    = (const float*)d_in[7];
    const float* Wr    = (const float*)d_in[8];
    const float* Wp    = (const float*)d_in[9];
    const float* bp    = (const float*)d_in[10];
    float* out = (float*)d_out;

    // ws layout (~105 MiB total)
    char* ws = (char*)d_ws;
    size_t off = 0;
    unsigned short* H    = (unsigned short*)(ws + off); off += (size_t)KPAD * DIMEMB * 2;
    unsigned short* WpTt = (unsigned short*)(ws + off); off += (size_t)DIMEMB * DIMIN * 2;
    unsigned short* W1Ts = (unsigned short*)(ws + off); off += (size_t)DIMATTN * DIMEMB * 2;
    float* Tpart = (float*)(ws + off); off += (size_t)3 * KPAD * 4;
    float* Spart = (float*)(ws + off); off += 1024;
    float* Mpart = (float*)(ws + off); off += (size_t)98 * DIMEMB * 4;

    k_prep<<<288, 256, 0, stream>>>(Wproj, W1, WpTt, W1Ts);
    k_gemm1<<<NB1, 256, 0, stream>>>(X, WpTt, bproj, H);
    k_gemm2<<<dim3(3, 782), 256, 0, stream>>>(H, W1Ts, b1, W2, Tpart);
    k_poolE<<<98, 512, 0, stream>>>(Tpart, H, b2, Spart, Mpart);
    k_head<<<1, 512, 0, stream>>>(Spart, Mpart, Wr, Xtfl, Wp, bp, out);
}